// Round 6
// baseline (251.386 us; speedup 1.0000x reference)
//
#include <hip/hip_runtime.h>
#include <hip/hip_bf16.h>
#include <stdint.h>

typedef unsigned short u16;
typedef unsigned int   u32;
typedef unsigned long long u64;
typedef __bf16 bf16x8 __attribute__((ext_vector_type(8)));
typedef short  s16x4  __attribute__((ext_vector_type(4)));
typedef float  f32x4  __attribute__((ext_vector_type(4)));

#define D_MODEL 1024
#define NH 16
#define DHEAD 64
#define BB 4
#define SS 2048
#define MM (BB*SS)   // 8192 rows

__device__ __forceinline__ u16 f2bf(float f) {
    unsigned int u = __float_as_uint(f);
    u += 0x7fffu + ((u >> 16) & 1u);   // RNE
    return (u16)(u >> 16);
}
__device__ __forceinline__ float bf2f(u16 s) {
    return __uint_as_float(((unsigned int)s) << 16);
}
__device__ __forceinline__ u32 pkbf(float a, float b) {  // v_cvt_pk_bf16_f32 (RNE)
    __hip_bfloat162 h = __float22bfloat162_rn(make_float2(a, b));
    return *(u32*)&h;
}

union U8 {
    uint4 q;
    u16   v[8];
    bf16x8 f;
};

// ---------------------------------------------------------------- merged cvt f32->bf16 (x, w_qkv, w_out)
#define N4X (MM * D_MODEL / 4)        // 2097152
#define N4W (D_MODEL * D_MODEL / 4)   // 262144
__global__ __launch_bounds__(256) void cvt_all_kernel(const float* __restrict__ x,
                                                      const float* __restrict__ wq,
                                                      const float* __restrict__ wo,
                                                      u16* __restrict__ xb,
                                                      u16* __restrict__ wqb,
                                                      u16* __restrict__ wob) {
    int i = blockIdx.x * 256 + threadIdx.x;
    const float* s; u16* d; int off;
    if (i < N4X)            { s = x;  d = xb;  off = i; }
    else if (i < N4X + N4W) { s = wq; d = wqb; off = i - N4X; }
    else                    { s = wo; d = wob; off = i - N4X - N4W; }
    float4 f = ((const float4*)s)[off];
    u32 o[2] = { pkbf(f.x, f.y), pkbf(f.z, f.w) };
    ((uint2*)d)[off] = *(const uint2*)o;
}

// ================================================================ GEMM core (BK=64, XOR-swizzled LDS)
template <bool PERMUTE_OUT>
__device__ __forceinline__ void gemm_body(const u16* __restrict__ A,
                                          const u16* __restrict__ Bt,
                                          const float* __restrict__ Bo,
                                          u16* __restrict__ Cq, u16* __restrict__ CqT,
                                          float* __restrict__ Out)
{
    __shared__ __align__(16) u16 As[128*64];
    __shared__ __align__(16) u16 Bs[128*64];

    const int tid  = threadIdx.x;
    const int wave = tid >> 6;
    const int lane = tid & 63;
    const int quad = lane >> 4;
    const int l16  = lane & 15;
    const int bm = blockIdx.x >> 3;
    const int bn = blockIdx.x & 7;
    const int wm = wave >> 1, wn = wave & 1;

    f32x4 acc[4][4] = {};

    const int rp = tid >> 3;              // row in 32-row pass
    const int ch = tid & 7;               // physical chunk (8 elems)
    const int sc = ch ^ (rp & 7);         // source (logical) chunk

    const u16* Ab = A  + (size_t)(bm * 128 + rp) * D_MODEL + sc * 8;
    const u16* Bb = Bt + (size_t)(bn * 128 + rp) * D_MODEL + sc * 8;
    const int xr = l16 & 7;

    for (int k0 = 0; k0 < D_MODEL; k0 += 64) {
#pragma unroll
        for (int p = 0; p < 4; ++p) {
            __builtin_amdgcn_global_load_lds(
                (__attribute__((address_space(1))) void*)(Ab + (size_t)(32*p) * D_MODEL + k0),
                (__attribute__((address_space(3))) void*)(As + p*2048 + tid*8), 16, 0, 0);
            __builtin_amdgcn_global_load_lds(
                (__attribute__((address_space(1))) void*)(Bb + (size_t)(32*p) * D_MODEL + k0),
                (__attribute__((address_space(3))) void*)(Bs + p*2048 + tid*8), 16, 0, 0);
        }
        __syncthreads();

#pragma unroll
        for (int ks = 0; ks < 2; ++ks) {
            bf16x8 af[4], bfr[4];
#pragma unroll
            for (int t = 0; t < 4; ++t)
                af[t] = *(const bf16x8*)(const void*)(
                    As + (wm*64 + t*16 + l16)*64 + (((ks*4 + quad) ^ xr) * 8));
#pragma unroll
            for (int t = 0; t < 4; ++t)
                bfr[t] = *(const bf16x8*)(const void*)(
                    Bs + (wn*64 + t*16 + l16)*64 + (((ks*4 + quad) ^ xr) * 8));
#pragma unroll
            for (int i = 0; i < 4; ++i)
#pragma unroll
                for (int j = 0; j < 4; ++j)
                    acc[i][j] = __builtin_amdgcn_mfma_f32_16x16x32_bf16(af[i], bfr[j], acc[i][j], 0, 0, 0);
        }
        __syncthreads();
    }

    const int rowbase = bm*128 + wm*64;
    const int colbase = bn*128 + wn*64;
    if (PERMUTE_OUT) {
#pragma unroll
        for (int j = 0; j < 4; ++j) {
            const int col = colbase + j*16 + l16;
            const int h = col >> 6, dh = col & 63;
#pragma unroll
            for (int i = 0; i < 4; ++i) {
                const int row0 = rowbase + i*16 + quad*4;
                const int b = row0 >> 11, s0 = row0 & (SS - 1);
#pragma unroll
                for (int r = 0; r < 4; ++r)
                    Cq[(((size_t)(b*NH + h))*SS + s0 + r)*DHEAD + dh] = f2bf(acc[i][j][r]);
                u64 w = (u64)pkbf(acc[i][j][0], acc[i][j][1])
                      | ((u64)pkbf(acc[i][j][2], acc[i][j][3]) << 32);
                *(u64*)(CqT + ((size_t)((b*NH + h)*DHEAD + dh))*SS + s0) = w;
            }
        }
    } else {
#pragma unroll
        for (int j = 0; j < 4; ++j) {
            const int col = colbase + j*16 + l16;
            const float bias = Bo[col];
#pragma unroll
            for (int i = 0; i < 4; ++i) {
#pragma unroll
                for (int r = 0; r < 4; ++r) {
                    const int row = rowbase + i*16 + quad*4 + r;
                    Out[(size_t)row * D_MODEL + col] = acc[i][j][r] + bias;
                }
            }
        }
    }
}

__global__ __launch_bounds__(256) void gemm_qkv_kernel(const u16* __restrict__ A,
                                                       const u16* __restrict__ Bt,
                                                       u16* __restrict__ Cq,
                                                       u16* __restrict__ CqT) {
    gemm_body<true>(A, Bt, nullptr, Cq, CqT, nullptr);
}

__global__ __launch_bounds__(256) void gemm_out_kernel(const u16* __restrict__ A,
                                                       const u16* __restrict__ Bt,
                                                       const float* __restrict__ Bo,
                                                       float* __restrict__ Out) {
    gemm_body<false>(A, Bt, Bo, nullptr, nullptr, Out);
}

// ---------------------------------------------------------------- attention (Q=K=V), S^T + register-P
// S^T = K*Q^T via 16x16x32; D layout (q=l16, key=quad*4+r) EQUALS the B-operand layout
// (n=l16, k=quad*4+j) of 16x16x16 MFMA -> exp2(S) feeds PV directly from registers.
// No P LDS round-trip. V A-frags are ds_read_b64. 2-wave blocks, grid 2048.
__global__ __launch_bounds__(128, 4) void attn_kernel(const u16* __restrict__ qkv,   // [B*H][2048][64]
                                                      const u16* __restrict__ qkvT,  // [B*H][64][2048]
                                                      u16* __restrict__ outb)        // [B][S][1024]
{
    __shared__ __align__(16) u16 Ks[2*2048];    // [buf][32 key][64 dh] chunk-swizzled, 8 KB
    __shared__ __align__(16) u16 Vt[2*2048];    // [buf][64 dh][32 key] chunk-swizzled, 8 KB

    const int tid  = threadIdx.x;    // 0..127 (2 waves)
    const int wave = tid >> 6;
    const int lane = tid & 63;
    const int quad = lane >> 4;
    const int l16  = lane & 15;

    const int bh   = blockIdx.x >> 5;   // 64
    const int qblk = blockIdx.x & 31;   // 32 q-blocks of 64 rows
    const int b = bh >> 4, h = bh & 15;
    const int qbase = qblk * 64 + wave * 32;

    const u16* Qp = qkv + (size_t)bh * SS * DHEAD;
    const float qscale = 0.125f * 1.4426950408889634f;  // 1/sqrt(64) * log2(e)

    // Q as B-operand frags for S^T (16x16x32): lane reads 8 consecutive dh at fixed q
    bf16x8 qb[2][2];
#pragma unroll
    for (int nt = 0; nt < 2; ++nt)
#pragma unroll
        for (int ks = 0; ks < 2; ++ks) {
            U8 raw; raw.q = *(const uint4*)(Qp + (size_t)(qbase + nt*16 + l16)*DHEAD + ks*32 + quad*8);
            U8 w;
#pragma unroll
            for (int jj = 0; jj < 4; ++jj)
                ((u32*)&w)[jj] = pkbf(bf2f(raw.v[2*jj]) * qscale, bf2f(raw.v[2*jj+1]) * qscale);
            qb[nt][ks] = w.f;
        }

    // DMA staging (128 threads; 2 instrs per tile): chunk-swizzled
    const int rK = tid >> 3;                         // 0..15 (+16 for 2nd instr)
    const int cK = (tid & 7) ^ ((rK >> 1) & 7);      // ((r+16)>>1)&7 == (r>>1)&7
    const u16* srcK = qkv  + (size_t)bh * SS * DHEAD + rK * DHEAD + cK * 8;
    const int rV = tid >> 2;                         // 0..31 (+32 for 2nd instr)
    const int cV = (tid & 3) ^ ((rV >> 1) & 3);
    const u16* srcV = qkvT + (size_t)bh * DHEAD * SS + (size_t)rV * SS + cV * 8;

    // K frag b128 offsets (A-operand of 16x16x32, un-swizzled)
    const int h8 = (l16 >> 1) & 7, h4 = (l16 >> 1) & 3;
    const int ko0 = l16*64 + ((quad)     ^ h8) * 8;
    const int ko1 = l16*64 + ((4 + quad) ^ h8) * 8;
    // V frag b64 offsets (A-operand of 16x16x16): 4 consecutive keys at fixed dh
    // logical chunk = kk*2 + (quad>>1), physical = ^h4, sub = (quad&1)*4 elems
    int vo[2];
#pragma unroll
    for (int kk = 0; kk < 2; ++kk)
        vo[kk] = l16*32 + (((kk*2 + (quad >> 1)) ^ h4) * 8) + (quad & 1)*4;

    s16x4 ones4;
#pragma unroll
    for (int j = 0; j < 4; ++j) ones4[j] = (short)0x3F80;

    f32x4 ot[4][2] = {};    // O^T[dh-tile][q-tile]
    f32x4 lsum[2]  = {};

    // prime buffer 0 (4 KB per tile = 2 instrs of 128 lanes x 16 B)
#pragma unroll
    for (int p = 0; p < 2; ++p) {
        __builtin_amdgcn_global_load_lds(
            (__attribute__((address_space(1))) void*)(srcK + p*16*DHEAD),
            (__attribute__((address_space(3))) void*)(Ks + p*1024 + tid*8), 16, 0, 0);
        __builtin_amdgcn_global_load_lds(
            (__attribute__((address_space(1))) void*)(srcV + (size_t)p*32*SS),
            (__attribute__((address_space(3))) void*)(Vt + p*1024 + tid*8), 16, 0, 0);
    }

#pragma unroll 2
    for (int kt = 0; kt < SS/32; ++kt) {
        __syncthreads();   // drains DMA for tile kt
        if (kt < SS/32 - 1) {   // prefetch kt+1 into other buffer
            const int bo = ((kt+1)&1) * 2048;
#pragma unroll
            for (int p = 0; p < 2; ++p) {
                __builtin_amdgcn_global_load_lds(
                    (__attribute__((address_space(1))) void*)(srcK + (size_t)((kt+1)*32 + p*16)*DHEAD),
                    (__attribute__((address_space(3))) void*)(Ks + bo + p*1024 + tid*8), 16, 0, 0);
                __builtin_amdgcn_global_load_lds(
                    (__attribute__((address_space(1))) void*)(srcV + (kt+1)*32 + (size_t)p*32*SS),
                    (__attribute__((address_space(3))) void*)(Vt + bo + p*1024 + tid*8), 16, 0, 0);
            }
        }
        const u16* Kb = Ks + (kt&1)*2048;
        const u16* Vb = Vt + (kt&1)*2048;

        // S^T = K * Q^T (exp2 domain), P stays in registers as PV B-frags
        s16x4 pf[2][2];   // [key-16-tile][q-tile]
#pragma unroll
        for (int mt = 0; mt < 2; ++mt) {
            f32x4 s[2] = {};
            bf16x8 kf0 = *(const bf16x8*)(const void*)(Kb + mt*1024 + ko0);
            bf16x8 kf1 = *(const bf16x8*)(const void*)(Kb + mt*1024 + ko1);
#pragma unroll
            for (int nt = 0; nt < 2; ++nt)
                s[nt] = __builtin_amdgcn_mfma_f32_16x16x32_bf16(kf0, qb[nt][0], s[nt], 0, 0, 0);
#pragma unroll
            for (int nt = 0; nt < 2; ++nt)
                s[nt] = __builtin_amdgcn_mfma_f32_16x16x32_bf16(kf1, qb[nt][1], s[nt], 0, 0, 0);
#pragma unroll
            for (int nt = 0; nt < 2; ++nt) {
                u32 lo = pkbf(__builtin_amdgcn_exp2f(s[nt][0]), __builtin_amdgcn_exp2f(s[nt][1]));
                u32 hi = pkbf(__builtin_amdgcn_exp2f(s[nt][2]), __builtin_amdgcn_exp2f(s[nt][3]));
                ((u32*)&pf[mt][nt])[0] = lo;
                ((u32*)&pf[mt][nt])[1] = hi;
            }
        }

        // lsum += 1 * P  (K=16 MFMA, register B-frags)
#pragma unroll
        for (int mt = 0; mt < 2; ++mt)
#pragma unroll
            for (int nt = 0; nt < 2; ++nt)
                lsum[nt] = __builtin_amdgcn_mfma_f32_16x16x16bf16_1k(ones4, pf[mt][nt], lsum[nt], 0, 0, 0);

        // O^T += V^T * P^T  (K=16 MFMAs; V frags are b64 reads)
#pragma unroll
        for (int dt = 0; dt < 4; ++dt) {
#pragma unroll
            for (int kk = 0; kk < 2; ++kk) {
                s16x4 vf = *(const s16x4*)(const void*)(Vb + dt*512 + vo[kk]);
#pragma unroll
                for (int nt = 0; nt < 2; ++nt)
                    ot[dt][nt] = __builtin_amdgcn_mfma_f32_16x16x16bf16_1k(vf, pf[kk][nt], ot[dt][nt], 0, 0, 0);
            }
        }
    }

    // epilogue: O = O^T / lsum, packed 8B stores (4 consecutive dh per lane)
    float inv[2];
#pragma unroll
    for (int nt = 0; nt < 2; ++nt) inv[nt] = 1.0f / lsum[nt][0];
#pragma unroll
    for (int dt = 0; dt < 4; ++dt)
#pragma unroll
        for (int nt = 0; nt < 2; ++nt) {
            u64 w = (u64)pkbf(ot[dt][nt][0]*inv[nt], ot[dt][nt][1]*inv[nt])
                  | ((u64)pkbf(ot[dt][nt][2]*inv[nt], ot[dt][nt][3]*inv[nt]) << 32);
            *(u64*)(outb + ((size_t)(b*SS + qbase + nt*16 + l16))*D_MODEL
                         + h*64 + dt*16 + quad*4) = w;
        }
}

// ---------------------------------------------------------------- launcher
extern "C" void kernel_launch(void* const* d_in, const int* in_sizes, int n_in,
                              void* d_out, int out_size, void* d_ws, size_t ws_size,
                              hipStream_t stream)
{
    (void)in_sizes; (void)n_in; (void)out_size; (void)ws_size;
    const float* x  = (const float*)d_in[0];
    const float* wq = (const float*)d_in[1];
    const float* wo = (const float*)d_in[2];
    const float* bo = (const float*)d_in[3];

    char* ws = (char*)d_ws;
    u16* xb    = (u16*)(ws);                          // 16 MiB  [8192][1024] bf16 x
    u16* wqb   = (u16*)(ws + (size_t)(16 << 20));     //  2 MiB
    u16* wob   = (u16*)(ws + (size_t)(18 << 20));     //  2 MiB
    u16* qkvb  = (u16*)(ws + (size_t)(20 << 20));     // 16 MiB  [64][2048][64]
    u16* qkvTb = (u16*)(ws + (size_t)(36 << 20));     // 16 MiB  [64][64][2048]
    u16* attb  = xb;                                  // reuse x-bf16 buffer for attention output

    cvt_all_kernel<<<(N4X + 2*N4W) / 256, 256, 0, stream>>>(x, wq, wo, xb, wqb, wob);
    gemm_qkv_kernel<<<(MM/128) * (D_MODEL/128), 256, 0, stream>>>(xb, wqb, qkvb, qkvTb);
    attn_kernel<<<BB * NH * (SS/64), 128, 0, stream>>>(qkvb, qkvTb, attb);
    gemm_out_kernel<<<(MM/128) * (D_MODEL/128), 256, 0, stream>>>(attb, wob, bo, (float*)d_out);
}

// Round 7
// 239.430 us; speedup vs baseline: 1.0499x; 1.0499x over previous
//
#include <hip/hip_runtime.h>
#include <hip/hip_bf16.h>
#include <stdint.h>

typedef unsigned short u16;
typedef unsigned int   u32;
typedef unsigned long long u64;
typedef __bf16 bf16x8 __attribute__((ext_vector_type(8)));
typedef float  f32x4  __attribute__((ext_vector_type(4)));

#define D_MODEL 1024
#define NH 16
#define DHEAD 64
#define BB 4
#define SS 2048
#define MM (BB*SS)   // 8192 rows

__device__ __forceinline__ u16 f2bf(float f) {
    unsigned int u = __float_as_uint(f);
    u += 0x7fffu + ((u >> 16) & 1u);   // RNE
    return (u16)(u >> 16);
}
__device__ __forceinline__ float bf2f(u16 s) {
    return __uint_as_float(((unsigned int)s) << 16);
}
__device__ __forceinline__ u32 pkbf(float a, float b) {  // v_cvt_pk_bf16_f32 (RNE)
    __hip_bfloat162 h = __float22bfloat162_rn(make_float2(a, b));
    return *(u32*)&h;
}

union U8 {
    uint4 q;
    u16   v[8];
    bf16x8 f;
};

// ---------------------------------------------------------------- merged cvt f32->bf16 (x, w_qkv, w_out)
#define N4X (MM * D_MODEL / 4)        // 2097152
#define N4W (D_MODEL * D_MODEL / 4)   // 262144
__global__ __launch_bounds__(256) void cvt_all_kernel(const float* __restrict__ x,
                                                      const float* __restrict__ wq,
                                                      const float* __restrict__ wo,
                                                      u16* __restrict__ xb,
                                                      u16* __restrict__ wqb,
                                                      u16* __restrict__ wob) {
    int i = blockIdx.x * 256 + threadIdx.x;
    const float* s; u16* d; int off;
    if (i < N4X)            { s = x;  d = xb;  off = i; }
    else if (i < N4X + N4W) { s = wq; d = wqb; off = i - N4X; }
    else                    { s = wo; d = wob; off = i - N4X - N4W; }
    float4 f = ((const float4*)s)[off];
    u32 o[2] = { pkbf(f.x, f.y), pkbf(f.z, f.w) };
    ((uint2*)d)[off] = *(const uint2*)o;
}

// ================================================================ GEMM core
// 128M x 64N tiles, BK=64, XOR-swizzled LDS, grid 1024 (= 4 blocks/CU, 16 waves/CU).
// Wave tile 64M x 32N -> acc[4][2] (32 VGPRs), 16 MFMA per wave-iter.
template <bool PERMUTE_OUT>
__device__ __forceinline__ void gemm_body(const u16* __restrict__ A,
                                          const u16* __restrict__ Bt,
                                          const float* __restrict__ Bo,
                                          u16* __restrict__ Cq, u16* __restrict__ CqT,
                                          float* __restrict__ Out)
{
    __shared__ __align__(16) u16 As[128*64];   // 16 KB
    __shared__ __align__(16) u16 Bs[64*64];    //  8 KB

    const int tid  = threadIdx.x;
    const int wave = tid >> 6;
    const int lane = tid & 63;
    const int quad = lane >> 4;
    const int l16  = lane & 15;
    const int bm = blockIdx.x >> 4;    // 64 M-tiles
    const int bn = blockIdx.x & 15;    // 16 N-tiles
    const int wm = wave >> 1, wn = wave & 1;

    f32x4 acc[4][2] = {};

    const int rp = tid >> 3;              // row in 32-row pass
    const int ch = tid & 7;               // physical chunk (8 elems)
    const int sc = ch ^ (rp & 7);         // source (logical) chunk

    const u16* Ab = A  + (size_t)(bm * 128 + rp) * D_MODEL + sc * 8;
    const u16* Bb = Bt + (size_t)(bn * 64 + rp) * D_MODEL + sc * 8;
    const int xr = l16 & 7;

    for (int k0 = 0; k0 < D_MODEL; k0 += 64) {
#pragma unroll
        for (int p = 0; p < 4; ++p)
            __builtin_amdgcn_global_load_lds(
                (__attribute__((address_space(1))) void*)(Ab + (size_t)(32*p) * D_MODEL + k0),
                (__attribute__((address_space(3))) void*)(As + p*2048 + tid*8), 16, 0, 0);
#pragma unroll
        for (int p = 0; p < 2; ++p)
            __builtin_amdgcn_global_load_lds(
                (__attribute__((address_space(1))) void*)(Bb + (size_t)(32*p) * D_MODEL + k0),
                (__attribute__((address_space(3))) void*)(Bs + p*2048 + tid*8), 16, 0, 0);
        __syncthreads();

#pragma unroll
        for (int ks = 0; ks < 2; ++ks) {
            bf16x8 af[4], bfr[2];
#pragma unroll
            for (int t = 0; t < 4; ++t)
                af[t] = *(const bf16x8*)(const void*)(
                    As + (wm*64 + t*16 + l16)*64 + (((ks*4 + quad) ^ xr) * 8));
#pragma unroll
            for (int j = 0; j < 2; ++j)
                bfr[j] = *(const bf16x8*)(const void*)(
                    Bs + (wn*32 + j*16 + l16)*64 + (((ks*4 + quad) ^ xr) * 8));
#pragma unroll
            for (int i = 0; i < 4; ++i)
#pragma unroll
                for (int j = 0; j < 2; ++j)
                    acc[i][j] = __builtin_amdgcn_mfma_f32_16x16x32_bf16(af[i], bfr[j], acc[i][j], 0, 0, 0);
        }
        __syncthreads();
    }

    const int rowbase = bm*128 + wm*64;
    const int colbase = bn*64 + wn*32;
    if (PERMUTE_OUT) {
#pragma unroll
        for (int j = 0; j < 2; ++j) {
            const int col = colbase + j*16 + l16;
            const int h = col >> 6, dh = col & 63;
#pragma unroll
            for (int i = 0; i < 4; ++i) {
                const int row0 = rowbase + i*16 + quad*4;
                const int b = row0 >> 11, s0 = row0 & (SS - 1);
#pragma unroll
                for (int r = 0; r < 4; ++r)
                    Cq[(((size_t)(b*NH + h))*SS + s0 + r)*DHEAD + dh] = f2bf(acc[i][j][r]);
                u64 w = (u64)pkbf(acc[i][j][0], acc[i][j][1])
                      | ((u64)pkbf(acc[i][j][2], acc[i][j][3]) << 32);
                *(u64*)(CqT + ((size_t)((b*NH + h)*DHEAD + dh))*SS + s0) = w;
            }
        }
    } else {
#pragma unroll
        for (int j = 0; j < 2; ++j) {
            const int col = colbase + j*16 + l16;
            const float bias = Bo[col];
#pragma unroll
            for (int i = 0; i < 4; ++i) {
#pragma unroll
                for (int r = 0; r < 4; ++r) {
                    const int row = rowbase + i*16 + quad*4 + r;
                    Out[(size_t)row * D_MODEL + col] = acc[i][j][r] + bias;
                }
            }
        }
    }
}

__global__ __launch_bounds__(256, 4) void gemm_qkv_kernel(const u16* __restrict__ A,
                                                          const u16* __restrict__ Bt,
                                                          u16* __restrict__ Cq,
                                                          u16* __restrict__ CqT) {
    gemm_body<true>(A, Bt, nullptr, Cq, CqT, nullptr);
}

__global__ __launch_bounds__(256, 4) void gemm_out_kernel(const u16* __restrict__ A,
                                                          const u16* __restrict__ Bt,
                                                          const float* __restrict__ Bo,
                                                          float* __restrict__ Out) {
    gemm_body<false>(A, Bt, Bo, nullptr, nullptr, Out);
}

// ---------------------------------------------------------------- attention (Q=K=V), S^T formulation
// REVERTED to round-5 (proven 104.7 us): 4-wave blocks, 32 q-cols/wave, grid 1024.
// S^T = K*Q^T -> D holds 4 consecutive keys/lane -> b64 P writes, b128 P reads as PV B-frags.
// O^T = V^T * P^T. K/V double-buffered via swizzled DMA; one barrier per kt.
__global__ __launch_bounds__(256, 4) void attn_kernel(const u16* __restrict__ qkv,   // [B*H][2048][64]
                                                      const u16* __restrict__ qkvT,  // [B*H][64][2048]
                                                      u16* __restrict__ outb)        // [B][S][1024]
{
    __shared__ __align__(16) u16 Ks[2*2048];    // [buf][32 key][64 dh] chunk-swizzled
    __shared__ __align__(16) u16 Vt[2*2048];    // [buf][64 dh][32 key] chunk-swizzled
    __shared__ __align__(16) u16 Pl[4*1280];    // per-wave [32 q][keys], stride 40

    const int tid  = threadIdx.x;
    const int wave = tid >> 6;
    const int lane = tid & 63;
    const int quad = lane >> 4;
    const int l16  = lane & 15;

    const int bh   = blockIdx.x >> 4;
    const int qblk = blockIdx.x & 15;
    const int b = bh >> 4, h = bh & 15;
    const int qbase = qblk * 128 + wave * 32;

    const u16* Qp = qkv + (size_t)bh * SS * DHEAD;
    const float qscale = 0.125f * 1.4426950408889634f;  // 1/sqrt(64) * log2(e)

    // Q as B-operand frags: B[k=dh][n=q], lane reads 8 consecutive dh at fixed q
    bf16x8 qb[2][2];
#pragma unroll
    for (int nt = 0; nt < 2; ++nt)
#pragma unroll
        for (int ks = 0; ks < 2; ++ks) {
            U8 raw; raw.q = *(const uint4*)(Qp + (size_t)(qbase + nt*16 + l16)*DHEAD + ks*32 + quad*8);
            U8 w;
#pragma unroll
            for (int jj = 0; jj < 4; ++jj)
                ((u32*)&w)[jj] = pkbf(bf2f(raw.v[2*jj]) * qscale, bf2f(raw.v[2*jj+1]) * qscale);
            qb[nt][ks] = w.f;
        }

    // DMA staging sources (chunk-swizzled so frag reads are conflict-free)
    const int rK = tid >> 3, cK = (tid & 7) ^ ((rK >> 1) & 7);
    const u16* srcK = qkv  + (size_t)bh * SS * DHEAD + rK * DHEAD + cK * 8;
    const int rV = tid >> 2, cV = (tid & 3) ^ ((rV >> 1) & 3);
    const u16* srcV = qkvT + (size_t)bh * DHEAD * SS + (size_t)rV * SS + cV * 8;

    // frag read offsets
    const int h8 = (l16 >> 1) & 7, h4 = (l16 >> 1) & 3;
    const int ko0 = l16*64 + ((quad)     ^ h8) * 8;   // ks=0
    const int ko1 = l16*64 + ((4 + quad) ^ h8) * 8;   // ks=1
    const int vo  = l16*32 + ((quad) ^ h4) * 8;

    u16* Pw       = Pl + wave*1280 + l16*40 + quad*4;
    const u16* Pr = Pl + wave*1280 + l16*40 + quad*8;

    bf16x8 ones;
#pragma unroll
    for (int j = 0; j < 8; ++j) ones[j] = (__bf16)1.0f;

    f32x4 ot[4][2] = {};    // O^T[dh-tile][q-tile]
    f32x4 lsum[2]  = {};

    // prime buffer 0
    __builtin_amdgcn_global_load_lds(
        (__attribute__((address_space(1))) void*)(srcK),
        (__attribute__((address_space(3))) void*)(Ks + tid*8), 16, 0, 0);
    __builtin_amdgcn_global_load_lds(
        (__attribute__((address_space(1))) void*)(srcV),
        (__attribute__((address_space(3))) void*)(Vt + tid*8), 16, 0, 0);

#pragma unroll 2
    for (int kt = 0; kt < SS/32; ++kt) {
        __syncthreads();   // drains DMA for tile kt
        if (kt < SS/32 - 1) {   // prefetch kt+1 into other buffer (in flight during compute)
            __builtin_amdgcn_global_load_lds(
                (__attribute__((address_space(1))) void*)(srcK + (size_t)(kt+1)*32*DHEAD),
                (__attribute__((address_space(3))) void*)(Ks + ((kt+1)&1)*2048 + tid*8), 16, 0, 0);
            __builtin_amdgcn_global_load_lds(
                (__attribute__((address_space(1))) void*)(srcV + (kt+1)*32),
                (__attribute__((address_space(3))) void*)(Vt + ((kt+1)&1)*2048 + tid*8), 16, 0, 0);
        }
        const u16* Kb = Ks + (kt&1)*2048;
        const u16* Vb = Vt + (kt&1)*2048;

        // S^T = K * Q^T, then P^T = exp2(S^T) -> LDS (b64 packed writes)
#pragma unroll
        for (int mt = 0; mt < 2; ++mt) {
            f32x4 s[2] = {};
            bf16x8 kf0 = *(const bf16x8*)(const void*)(Kb + mt*1024 + ko0);
            bf16x8 kf1 = *(const bf16x8*)(const void*)(Kb + mt*1024 + ko1);
#pragma unroll
            for (int nt = 0; nt < 2; ++nt)
                s[nt] = __builtin_amdgcn_mfma_f32_16x16x32_bf16(kf0, qb[nt][0], s[nt], 0, 0, 0);
#pragma unroll
            for (int nt = 0; nt < 2; ++nt)
                s[nt] = __builtin_amdgcn_mfma_f32_16x16x32_bf16(kf1, qb[nt][1], s[nt], 0, 0, 0);
#pragma unroll
            for (int nt = 0; nt < 2; ++nt) {
                float p0 = __builtin_amdgcn_exp2f(s[nt][0]);
                float p1 = __builtin_amdgcn_exp2f(s[nt][1]);
                float p2 = __builtin_amdgcn_exp2f(s[nt][2]);
                float p3 = __builtin_amdgcn_exp2f(s[nt][3]);
                u64 w = (u64)pkbf(p0, p1) | ((u64)pkbf(p2, p3) << 32);
                *(u64*)(Pw + nt*640 + mt*16) = w;
            }
        }

        // P^T frags (B-operand: 8 consecutive keys at fixed q) + V^T frags (A-operand)
        bf16x8 pf[2];
#pragma unroll
        for (int nt = 0; nt < 2; ++nt)
            pf[nt] = *(const bf16x8*)(const void*)(Pr + nt*640);
#pragma unroll
        for (int nt = 0; nt < 2; ++nt)
            lsum[nt] = __builtin_amdgcn_mfma_f32_16x16x32_bf16(ones, pf[nt], lsum[nt], 0, 0, 0);
        bf16x8 vf[4];
#pragma unroll
        for (int dt = 0; dt < 4; ++dt)
            vf[dt] = *(const bf16x8*)(const void*)(Vb + dt*512 + vo);
#pragma unroll
        for (int dt = 0; dt < 4; ++dt)
#pragma unroll
            for (int nt = 0; nt < 2; ++nt)
                ot[dt][nt] = __builtin_amdgcn_mfma_f32_16x16x32_bf16(vf[dt], pf[nt], ot[dt][nt], 0, 0, 0);
    }

    // epilogue: O = O^T / lsum, packed 8B stores (4 consecutive dh per lane)
    float inv[2];
#pragma unroll
    for (int nt = 0; nt < 2; ++nt) inv[nt] = 1.0f / lsum[nt][0];
#pragma unroll
    for (int dt = 0; dt < 4; ++dt)
#pragma unroll
        for (int nt = 0; nt < 2; ++nt) {
            u64 w = (u64)pkbf(ot[dt][nt][0]*inv[nt], ot[dt][nt][1]*inv[nt])
                  | ((u64)pkbf(ot[dt][nt][2]*inv[nt], ot[dt][nt][3]*inv[nt]) << 32);
            *(u64*)(outb + ((size_t)(b*SS + qbase + nt*16 + l16))*D_MODEL
                         + h*64 + dt*16 + quad*4) = w;
        }
}

// ---------------------------------------------------------------- launcher
extern "C" void kernel_launch(void* const* d_in, const int* in_sizes, int n_in,
                              void* d_out, int out_size, void* d_ws, size_t ws_size,
                              hipStream_t stream)
{
    (void)in_sizes; (void)n_in; (void)out_size; (void)ws_size;
    const float* x  = (const float*)d_in[0];
    const float* wq = (const float*)d_in[1];
    const float* wo = (const float*)d_in[2];
    const float* bo = (const float*)d_in[3];

    char* ws = (char*)d_ws;
    u16* xb    = (u16*)(ws);                          // 16 MiB  [8192][1024] bf16 x
    u16* wqb   = (u16*)(ws + (size_t)(16 << 20));     //  2 MiB
    u16* wob   = (u16*)(ws + (size_t)(18 << 20));     //  2 MiB
    u16* qkvb  = (u16*)(ws + (size_t)(20 << 20));     // 16 MiB  [64][2048][64]
    u16* qkvTb = (u16*)(ws + (size_t)(36 << 20));     // 16 MiB  [64][64][2048]
    u16* attb  = xb;                                  // reuse x-bf16 buffer for attention output

    cvt_all_kernel<<<(N4X + 2*N4W) / 256, 256, 0, stream>>>(x, wq, wo, xb, wqb, wob);
    gemm_qkv_kernel<<<(MM/128) * (D_MODEL/64), 256, 0, stream>>>(xb, wqb, qkvb, qkvTb);
    attn_kernel<<<BB * NH * (SS/128), 256, 0, stream>>>(qkvb, qkvTb, attb);
    gemm_out_kernel<<<(MM/128) * (D_MODEL/64), 256, 0, stream>>>(attb, wob, bo, (float*)d_out);
}